// Round 1
// baseline (3141.495 us; speedup 1.0000x reference)
//
#include <hip/hip_runtime.h>
#include <cstddef>

#define NODES  100000
#define EDGES  3200000
#define ETOT   3300000   // EDGES + NODES self-loops
#define NGRAPH 64
#define HDIM   256       // hidden dim (layers 1/2 output)

// ---------------------------------------------------------------- init / degree
__global__ void init_kernel(int* __restrict__ deg, float* __restrict__ sums,
                            int* __restrict__ cnt) {
    int i = blockIdx.x * 256 + threadIdx.x;
    if (i < NODES) deg[i] = 1;                 // self-loop
    if (i < NGRAPH * HDIM) sums[i] = 0.f;
    if (i < NGRAPH) cnt[i] = 0;
}

__global__ void count_kernel(const int* __restrict__ col, int* __restrict__ deg) {
    int e = blockIdx.x * 256 + threadIdx.x;
    if (e < EDGES) atomicAdd(&deg[col[e]], 1);
}

__global__ void node_kernel(const int* __restrict__ deg, const int* __restrict__ batch,
                            float* __restrict__ dinv, int* __restrict__ cnt) {
    int i = blockIdx.x * 256 + threadIdx.x;
    if (i < NODES) {
        dinv[i] = rsqrtf((float)deg[i]);       // deg >= 1 always (self-loop)
        atomicAdd(&cnt[batch[i]], 1);
    }
}

// ---------------------------------------------------------------- exclusive scan (1 block)
__global__ __launch_bounds__(1024) void scan_kernel(const int* __restrict__ deg,
                                                    int* __restrict__ rowptr,
                                                    int* __restrict__ cursor) {
    __shared__ int part[1024];
    int t = threadIdx.x;
    const int C = (NODES + 1023) / 1024;       // 98
    int lo = t * C;
    int hi = lo + C; if (hi > NODES) hi = NODES;
    int s = 0;
    for (int i = lo; i < hi; i++) s += deg[i];
    part[t] = s;
    __syncthreads();
    for (int off = 1; off < 1024; off <<= 1) {
        int v = (t >= off) ? part[t - off] : 0;
        __syncthreads();
        part[t] += v;
        __syncthreads();
    }
    int run = (t == 0) ? 0 : part[t - 1];
    for (int i = lo; i < hi; i++) { rowptr[i] = run; cursor[i] = run; run += deg[i]; }
    if (t == 1023) rowptr[NODES] = part[1023]; // == ETOT
}

// ---------------------------------------------------------------- CSR fill (dest-sorted)
__global__ void fill_kernel(const int* __restrict__ row, const int* __restrict__ col,
                            int* __restrict__ cursor, int* __restrict__ csr) {
    int e = blockIdx.x * 256 + threadIdx.x;
    if (e >= ETOT) return;
    int r, c;
    if (e < EDGES) { r = row[e]; c = col[e]; }
    else           { r = e - EDGES; c = r; }   // self-loop
    int pos = atomicAdd(&cursor[c], 1);
    csr[pos] = r;
}

// ---------------------------------------------------------------- pull aggregation, H=128
// out[v] = dinv[v] * sum_{e:col=v} dinv[src] * x[src]   (one wave per node)
__global__ void agg1_kernel(const float* __restrict__ x, const int* __restrict__ rowptr,
                            const int* __restrict__ csr, const float* __restrict__ dinv,
                            float* __restrict__ out) {
    int w = (blockIdx.x * blockDim.x + threadIdx.x) >> 6;
    int lane = threadIdx.x & 63;
    if (w >= NODES) return;
    int beg = rowptr[w], end = rowptr[w + 1];
    const float2* x2 = (const float2*)x;       // 64 float2 per row (H=128)
    float2 acc = {0.f, 0.f};
    int j = beg;
    for (; j + 1 < end; j += 2) {
        int s0 = csr[j], s1 = csr[j + 1];
        float w0 = dinv[s0], w1 = dinv[s1];
        float2 v0 = x2[(size_t)s0 * 64 + lane];
        float2 v1 = x2[(size_t)s1 * 64 + lane];
        acc.x += w0 * v0.x + w1 * v1.x;
        acc.y += w0 * v0.y + w1 * v1.y;
    }
    if (j < end) {
        int s0 = csr[j];
        float w0 = dinv[s0];
        float2 v0 = x2[(size_t)s0 * 64 + lane];
        acc.x += w0 * v0.x;
        acc.y += w0 * v0.y;
    }
    float d = dinv[w];
    float2 o = {acc.x * d, acc.y * d};
    ((float2*)out)[(size_t)w * 64 + lane] = o;
}

// ---------------------------------------------------------------- pull aggregation, H=256
__global__ void agg2_kernel(const float* __restrict__ h, const int* __restrict__ rowptr,
                            const int* __restrict__ csr, const float* __restrict__ dinv,
                            float* __restrict__ out) {
    int w = (blockIdx.x * blockDim.x + threadIdx.x) >> 6;
    int lane = threadIdx.x & 63;
    if (w >= NODES) return;
    int beg = rowptr[w], end = rowptr[w + 1];
    const float4* h4 = (const float4*)h;       // 64 float4 per row (H=256)
    float4 acc = {0.f, 0.f, 0.f, 0.f};
    int j = beg;
    for (; j + 1 < end; j += 2) {
        int s0 = csr[j], s1 = csr[j + 1];
        float w0 = dinv[s0], w1 = dinv[s1];
        float4 v0 = h4[(size_t)s0 * 64 + lane];
        float4 v1 = h4[(size_t)s1 * 64 + lane];
        acc.x += w0 * v0.x + w1 * v1.x;
        acc.y += w0 * v0.y + w1 * v1.y;
        acc.z += w0 * v0.z + w1 * v1.z;
        acc.w += w0 * v0.w + w1 * v1.w;
    }
    if (j < end) {
        int s0 = csr[j];
        float w0 = dinv[s0];
        float4 v0 = h4[(size_t)s0 * 64 + lane];
        acc.x += w0 * v0.x; acc.y += w0 * v0.y;
        acc.z += w0 * v0.z; acc.w += w0 * v0.w;
    }
    float d = dinv[w];
    float4 o = {acc.x * d, acc.y * d, acc.z * d, acc.w * d};
    ((float4*)out)[(size_t)w * 64 + lane] = o;
}

// ---------------------------------------------------------------- fp32 register-tiled GEMM
// C[M,256] = relu(A[M,K] @ B[K,256] + bias).  POOL: atomicAdd into per-graph sums.
template <int K, bool POOL>
__global__ __launch_bounds__(256) void gemm_kernel(const float* __restrict__ A,
                                                   const float* __restrict__ B,
                                                   const float* __restrict__ bias,
                                                   float* __restrict__ Cout,
                                                   const int* __restrict__ batch,
                                                   float* __restrict__ sums) {
    constexpr int BM = 64, BN = 64, BK = 32;
    __shared__ float As[BK][BM + 4];   // +4 keeps float4 alignment, breaks pow2 stride
    __shared__ float Bs[BK][BN + 4];
    int tx = threadIdx.x;
    int bm = (blockIdx.x >> 2) * BM;
    int bn = (blockIdx.x & 3) * BN;
    int trow = tx >> 4, tcol = tx & 15;
    float acc[4][4] = {};

    for (int k0 = 0; k0 < K; k0 += BK) {
        // A tile 64x32: 256 threads x 2 float4, transposed store As[k][m]
        {
            int m  = tx >> 3;            // 0..31
            int k4 = (tx & 7) * 4;       // 0,4,...,28
            #pragma unroll
            for (int h = 0; h < 2; h++) {
                int mm  = m + h * 32;
                int row = bm + mm;
                float4 v = {0.f, 0.f, 0.f, 0.f};
                if (row < NODES) v = *(const float4*)(A + (size_t)row * K + k0 + k4);
                As[k4 + 0][mm] = v.x; As[k4 + 1][mm] = v.y;
                As[k4 + 2][mm] = v.z; As[k4 + 3][mm] = v.w;
            }
            int kk = tx >> 4;            // 0..15
            int n4 = (tx & 15) * 4;      // 0..60
            #pragma unroll
            for (int h = 0; h < 2; h++) {
                int k = kk + h * 16;
                float4 v = *(const float4*)(B + (size_t)(k0 + k) * 256 + bn + n4);
                *(float4*)&Bs[k][n4] = v;
            }
        }
        __syncthreads();
        #pragma unroll
        for (int k = 0; k < BK; k++) {
            float4 a = *(const float4*)&As[k][trow * 4];
            float4 b = *(const float4*)&Bs[k][tcol * 4];
            float av[4] = {a.x, a.y, a.z, a.w};
            float bv[4] = {b.x, b.y, b.z, b.w};
            #pragma unroll
            for (int i = 0; i < 4; i++)
                #pragma unroll
                for (int j = 0; j < 4; j++)
                    acc[i][j] += av[i] * bv[j];
        }
        __syncthreads();
    }

    int cbase = bn + tcol * 4;
    if (!POOL) {
        #pragma unroll
        for (int i = 0; i < 4; i++) {
            int row = bm + trow * 4 + i;
            if (row >= NODES) continue;
            float4 v;
            v.x = fmaxf(acc[i][0] + bias[cbase + 0], 0.f);
            v.y = fmaxf(acc[i][1] + bias[cbase + 1], 0.f);
            v.z = fmaxf(acc[i][2] + bias[cbase + 2], 0.f);
            v.w = fmaxf(acc[i][3] + bias[cbase + 3], 0.f);
            *(float4*)(Cout + (size_t)row * 256 + cbase) = v;
        }
    } else {
        #pragma unroll
        for (int i = 0; i < 4; i++) {
            int row = bm + trow * 4 + i;
            if (row >= NODES) continue;
            int g = batch[row];
            #pragma unroll
            for (int j = 0; j < 4; j++) {
                float v = fmaxf(acc[i][j] + bias[cbase + j], 0.f);
                atomicAdd(&sums[g * 256 + cbase + j], v);
            }
        }
    }
}

// ---------------------------------------------------------------- pooled @ Wl + bl
__global__ void final_kernel(const float* __restrict__ sums, const int* __restrict__ cnt,
                             const float* __restrict__ Wl, const float* __restrict__ bl,
                             float* __restrict__ out) {
    int g = blockIdx.x;
    int l = threadIdx.x;
    float inv = 1.f / fmaxf((float)cnt[g], 1.f);
    float a0 = 0.f, a1 = 0.f;
    for (int k = l; k < 256; k += 64) {
        float p = sums[g * 256 + k] * inv;
        a0 += p * Wl[k * 2 + 0];
        a1 += p * Wl[k * 2 + 1];
    }
    for (int off = 32; off > 0; off >>= 1) {
        a0 += __shfl_down(a0, off, 64);
        a1 += __shfl_down(a1, off, 64);
    }
    if (l == 0) {
        out[g * 2 + 0] = a0 + bl[0];
        out[g * 2 + 1] = a1 + bl[1];
    }
}

// ---------------------------------------------------------------- launch
extern "C" void kernel_launch(void* const* d_in, const int* in_sizes, int n_in,
                              void* d_out, int out_size, void* d_ws, size_t ws_size,
                              hipStream_t stream) {
    const float* x    = (const float*)d_in[0];
    const int*   ei   = (const int*)d_in[1];
    const int*   bat  = (const int*)d_in[2];
    const float* W1   = (const float*)d_in[3];
    const float* b1   = (const float*)d_in[4];
    const float* W2   = (const float*)d_in[5];
    const float* b2   = (const float*)d_in[6];
    const float* Wl   = (const float*)d_in[7];
    const float* bl   = (const float*)d_in[8];
    float*       out  = (float*)d_out;
    const int* erow = ei;           // edge_index[0] = source
    const int* ecol = ei + EDGES;   // edge_index[1] = target

    char* p = (char*)d_ws;
    auto take = [&](size_t bytes) {
        char* r = p;
        p += (bytes + 255) & ~(size_t)255;
        return r;
    };
    int*   deg    = (int*)  take((size_t)NODES * 4);
    float* dinv   = (float*)take((size_t)NODES * 4);
    int*   rowptr = (int*)  take((size_t)(NODES + 1) * 4);
    int*   cursor = (int*)  take((size_t)NODES * 4);
    int*   csr    = (int*)  take((size_t)ETOT * 4);
    float* sums   = (float*)take((size_t)NGRAPH * HDIM * 4);
    int*   cnt    = (int*)  take((size_t)NGRAPH * 4);
    float* h1     = (float*)take((size_t)NODES * HDIM * 4);
    float* aggbuf = (float*)take((size_t)NODES * HDIM * 4); // aggx (128) then aggh (256)

    const int NB = (NODES + 255) / 256;
    init_kernel <<<NB, 256, 0, stream>>>(deg, sums, cnt);
    count_kernel<<<(EDGES + 255) / 256, 256, 0, stream>>>(ecol, deg);
    node_kernel <<<NB, 256, 0, stream>>>(deg, bat, dinv, cnt);
    scan_kernel <<<1, 1024, 0, stream>>>(deg, rowptr, cursor);
    fill_kernel <<<(ETOT + 255) / 256, 256, 0, stream>>>(erow, ecol, cursor, csr);

    const int AGG_BLOCKS = (NODES * 64 + 255) / 256;  // one wave per node
    agg1_kernel<<<AGG_BLOCKS, 256, 0, stream>>>(x, rowptr, csr, dinv, aggbuf);

    const int MB = (NODES + 63) / 64;
    gemm_kernel<128, false><<<MB * 4, 256, 0, stream>>>(aggbuf, W1, b1, h1, nullptr, nullptr);

    agg2_kernel<<<AGG_BLOCKS, 256, 0, stream>>>(h1, rowptr, csr, dinv, aggbuf);

    gemm_kernel<256, true><<<MB * 4, 256, 0, stream>>>(aggbuf, W2, b2, nullptr, bat, sums);

    final_kernel<<<NGRAPH, 64, 0, stream>>>(sums, cnt, Wl, bl, out);
}

// Round 2
// 2359.694 us; speedup vs baseline: 1.3313x; 1.3313x over previous
//
#include <hip/hip_runtime.h>
#include <cstddef>

#define NODES  100000
#define EDGES  3200000
#define ETOT   3300000   // EDGES + NODES self-loops
#define NGRAPH 64
#define HDIM   256       // hidden dim (layers 1/2 output)

// ---------------------------------------------------------------- init / degree
__global__ void init_kernel(int* __restrict__ deg, float* __restrict__ sums,
                            int* __restrict__ cnt) {
    int i = blockIdx.x * 256 + threadIdx.x;
    if (i < NODES) deg[i] = 1;                 // self-loop
    if (i < NGRAPH * HDIM) sums[i] = 0.f;
    if (i < NGRAPH) cnt[i] = 0;
}

__global__ void count_kernel(const int* __restrict__ col, int* __restrict__ deg) {
    int e = blockIdx.x * 256 + threadIdx.x;
    if (e < EDGES) atomicAdd(&deg[col[e]], 1);
}

__global__ void node_kernel(const int* __restrict__ deg, const int* __restrict__ batch,
                            float* __restrict__ dinv, int* __restrict__ cnt) {
    int i = blockIdx.x * 256 + threadIdx.x;
    if (i < NODES) {
        dinv[i] = rsqrtf((float)deg[i]);       // deg >= 1 always (self-loop)
        atomicAdd(&cnt[batch[i]], 1);
    }
}

// ---------------------------------------------------------------- exclusive scan (1 block)
__global__ __launch_bounds__(1024) void scan_kernel(const int* __restrict__ deg,
                                                    int* __restrict__ rowptr,
                                                    int* __restrict__ cursor) {
    __shared__ int part[1024];
    int t = threadIdx.x;
    const int C = (NODES + 1023) / 1024;       // 98
    int lo = t * C;
    int hi = lo + C; if (hi > NODES) hi = NODES;
    int s = 0;
    for (int i = lo; i < hi; i++) s += deg[i];
    part[t] = s;
    __syncthreads();
    for (int off = 1; off < 1024; off <<= 1) {
        int v = (t >= off) ? part[t - off] : 0;
        __syncthreads();
        part[t] += v;
        __syncthreads();
    }
    int run = (t == 0) ? 0 : part[t - 1];
    for (int i = lo; i < hi; i++) { rowptr[i] = run; cursor[i] = run; run += deg[i]; }
    if (t == 1023) rowptr[NODES] = part[1023]; // == ETOT
}

// ---------------------------------------------------------------- CSR fill (dest-sorted)
__global__ void fill_kernel(const int* __restrict__ row, const int* __restrict__ col,
                            int* __restrict__ cursor, int* __restrict__ csr) {
    int e = blockIdx.x * 256 + threadIdx.x;
    if (e >= ETOT) return;
    int r, c;
    if (e < EDGES) { r = row[e]; c = col[e]; }
    else           { r = e - EDGES; c = r; }   // self-loop
    int pos = atomicAdd(&cursor[c], 1);
    csr[pos] = r;
}

// ---------------------------------------------------------------- pull aggregation, H=128
// out[v] = dinv[v] * sum_{e:col=v} dinv[src] * x[src]   (one wave per node)
__global__ void agg1_kernel(const float* __restrict__ x, const int* __restrict__ rowptr,
                            const int* __restrict__ csr, const float* __restrict__ dinv,
                            float* __restrict__ out) {
    int w = (blockIdx.x * blockDim.x + threadIdx.x) >> 6;
    int lane = threadIdx.x & 63;
    if (w >= NODES) return;
    int beg = rowptr[w], end = rowptr[w + 1];
    const float2* x2 = (const float2*)x;       // 64 float2 per row (H=128)
    float2 acc = {0.f, 0.f};
    int j = beg;
    for (; j + 1 < end; j += 2) {
        int s0 = csr[j], s1 = csr[j + 1];
        float w0 = dinv[s0], w1 = dinv[s1];
        float2 v0 = x2[(size_t)s0 * 64 + lane];
        float2 v1 = x2[(size_t)s1 * 64 + lane];
        acc.x += w0 * v0.x + w1 * v1.x;
        acc.y += w0 * v0.y + w1 * v1.y;
    }
    if (j < end) {
        int s0 = csr[j];
        float w0 = dinv[s0];
        float2 v0 = x2[(size_t)s0 * 64 + lane];
        acc.x += w0 * v0.x;
        acc.y += w0 * v0.y;
    }
    float d = dinv[w];
    float2 o = {acc.x * d, acc.y * d};
    ((float2*)out)[(size_t)w * 64 + lane] = o;
}

// ---------------------------------------------------------------- pull aggregation, H=256
__global__ void agg2_kernel(const float* __restrict__ h, const int* __restrict__ rowptr,
                            const int* __restrict__ csr, const float* __restrict__ dinv,
                            float* __restrict__ out) {
    int w = (blockIdx.x * blockDim.x + threadIdx.x) >> 6;
    int lane = threadIdx.x & 63;
    if (w >= NODES) return;
    int beg = rowptr[w], end = rowptr[w + 1];
    const float4* h4 = (const float4*)h;       // 64 float4 per row (H=256)
    float4 acc = {0.f, 0.f, 0.f, 0.f};
    int j = beg;
    for (; j + 1 < end; j += 2) {
        int s0 = csr[j], s1 = csr[j + 1];
        float w0 = dinv[s0], w1 = dinv[s1];
        float4 v0 = h4[(size_t)s0 * 64 + lane];
        float4 v1 = h4[(size_t)s1 * 64 + lane];
        acc.x += w0 * v0.x + w1 * v1.x;
        acc.y += w0 * v0.y + w1 * v1.y;
        acc.z += w0 * v0.z + w1 * v1.z;
        acc.w += w0 * v0.w + w1 * v1.w;
    }
    if (j < end) {
        int s0 = csr[j];
        float w0 = dinv[s0];
        float4 v0 = h4[(size_t)s0 * 64 + lane];
        acc.x += w0 * v0.x; acc.y += w0 * v0.y;
        acc.z += w0 * v0.z; acc.w += w0 * v0.w;
    }
    float d = dinv[w];
    float4 o = {acc.x * d, acc.y * d, acc.z * d, acc.w * d};
    ((float4*)out)[(size_t)w * 64 + lane] = o;
}

// ---------------------------------------------------------------- fp32 GEMM 128x128, 8x8/thread
// C[M,256] = relu(A[M,K] @ B[K,256] + bias), plain stores (no atomics).
template <int K>
__global__ __launch_bounds__(256) void gemm_kernel(const float* __restrict__ A,
                                                   const float* __restrict__ B,
                                                   const float* __restrict__ bias,
                                                   float* __restrict__ C) {
    constexpr int BM = 128, BN = 128, BK = 16;
    __shared__ float As[BK][BM];   // transposed A tile: As[k][m]
    __shared__ float Bs[BK][BN];
    const int t  = threadIdx.x;
    const int bm = (int)(blockIdx.x >> 1) * BM;
    const int bn = (int)(blockIdx.x & 1) * BN;
    const int tx = t & 15, ty = t >> 4;
    float acc[8][8] = {};

    for (int k0 = 0; k0 < K; k0 += BK) {
        // stage A tile (128x16): 512 float4, 2 per thread, store transposed
        #pragma unroll
        for (int h = 0; h < 2; h++) {
            int q  = t * 2 + h;
            int m  = q >> 2;           // 0..127
            int k4 = (q & 3) * 4;      // 0,4,8,12
            int row = bm + m;
            float4 v = {0.f, 0.f, 0.f, 0.f};
            if (row < NODES) v = *(const float4*)(A + (size_t)row * K + k0 + k4);
            As[k4 + 0][m] = v.x; As[k4 + 1][m] = v.y;
            As[k4 + 2][m] = v.z; As[k4 + 3][m] = v.w;
        }
        // stage B tile (16x128): 512 float4, 2 per thread
        #pragma unroll
        for (int h = 0; h < 2; h++) {
            int q  = t * 2 + h;
            int k  = q >> 5;           // 0..15
            int n4 = (q & 31) * 4;     // 0..124
            *(float4*)&Bs[k][n4] = *(const float4*)(B + (size_t)(k0 + k) * 256 + bn + n4);
        }
        __syncthreads();
        #pragma unroll
        for (int k = 0; k < BK; k++) {
            float a0[4], a1[4], b0[4], b1[4];
            *(float4*)a0 = *(const float4*)&As[k][ty * 4];
            *(float4*)a1 = *(const float4*)&As[k][64 + ty * 4];
            *(float4*)b0 = *(const float4*)&Bs[k][tx * 4];
            *(float4*)b1 = *(const float4*)&Bs[k][64 + tx * 4];
            #pragma unroll
            for (int i = 0; i < 4; i++) {
                #pragma unroll
                for (int j = 0; j < 4; j++) {
                    acc[i][j]         += a0[i] * b0[j];
                    acc[i][j + 4]     += a0[i] * b1[j];
                    acc[i + 4][j]     += a1[i] * b0[j];
                    acc[i + 4][j + 4] += a1[i] * b1[j];
                }
            }
        }
        __syncthreads();
    }

    #pragma unroll
    for (int ih = 0; ih < 2; ih++) {
        #pragma unroll
        for (int i = 0; i < 4; i++) {
            int row = bm + ih * 64 + ty * 4 + i;
            if (row >= NODES) continue;
            #pragma unroll
            for (int jh = 0; jh < 2; jh++) {
                int cb = bn + jh * 64 + tx * 4;
                float4 v;
                v.x = fmaxf(acc[ih * 4 + i][jh * 4 + 0] + bias[cb + 0], 0.f);
                v.y = fmaxf(acc[ih * 4 + i][jh * 4 + 1] + bias[cb + 1], 0.f);
                v.z = fmaxf(acc[ih * 4 + i][jh * 4 + 2] + bias[cb + 2], 0.f);
                v.w = fmaxf(acc[ih * 4 + i][jh * 4 + 3] + bias[cb + 3], 0.f);
                *(float4*)(C + (size_t)row * 256 + cb) = v;
            }
        }
    }
}

// ---------------------------------------------------------------- segmented mean-pool sum
// batch is SORTED: accumulate per-thread over contiguous row chunk, flush one
// atomicAdd per graph-boundary crossing. block: rows [bx*1024,+1024) x cols [by*64,+64)
__global__ void pool_kernel(const float* __restrict__ h2, const int* __restrict__ batch,
                            float* __restrict__ sums) {
    int lane = threadIdx.x & 63;
    int sub  = threadIdx.x >> 6;                   // 0..3
    int col  = blockIdx.y * 64 + lane;
    int r0   = blockIdx.x * 1024 + sub * 256;
    if (r0 >= NODES) return;
    int r1 = r0 + 256; if (r1 > NODES) r1 = NODES;
    float acc = 0.f;
    int g = batch[r0];
    for (int r = r0; r < r1; r++) {
        int gg = batch[r];
        if (gg != g) { atomicAdd(&sums[g * 256 + col], acc); acc = 0.f; g = gg; }
        acc += h2[(size_t)r * 256 + col];
    }
    atomicAdd(&sums[g * 256 + col], acc);
}

// ---------------------------------------------------------------- pooled @ Wl + bl
__global__ void final_kernel(const float* __restrict__ sums, const int* __restrict__ cnt,
                             const float* __restrict__ Wl, const float* __restrict__ bl,
                             float* __restrict__ out) {
    int g = blockIdx.x;
    int l = threadIdx.x;
    float inv = 1.f / fmaxf((float)cnt[g], 1.f);
    float a0 = 0.f, a1 = 0.f;
    for (int k = l; k < 256; k += 64) {
        float p = sums[g * 256 + k] * inv;
        a0 += p * Wl[k * 2 + 0];
        a1 += p * Wl[k * 2 + 1];
    }
    for (int off = 32; off > 0; off >>= 1) {
        a0 += __shfl_down(a0, off, 64);
        a1 += __shfl_down(a1, off, 64);
    }
    if (l == 0) {
        out[g * 2 + 0] = a0 + bl[0];
        out[g * 2 + 1] = a1 + bl[1];
    }
}

// ---------------------------------------------------------------- launch
extern "C" void kernel_launch(void* const* d_in, const int* in_sizes, int n_in,
                              void* d_out, int out_size, void* d_ws, size_t ws_size,
                              hipStream_t stream) {
    const float* x    = (const float*)d_in[0];
    const int*   ei   = (const int*)d_in[1];
    const int*   bat  = (const int*)d_in[2];
    const float* W1   = (const float*)d_in[3];
    const float* b1   = (const float*)d_in[4];
    const float* W2   = (const float*)d_in[5];
    const float* b2   = (const float*)d_in[6];
    const float* Wl   = (const float*)d_in[7];
    const float* bl   = (const float*)d_in[8];
    float*       out  = (float*)d_out;
    const int* erow = ei;           // edge_index[0] = source
    const int* ecol = ei + EDGES;   // edge_index[1] = target

    char* p = (char*)d_ws;
    auto take = [&](size_t bytes) {
        char* r = p;
        p += (bytes + 255) & ~(size_t)255;
        return r;
    };
    int*   deg    = (int*)  take((size_t)NODES * 4);
    float* dinv   = (float*)take((size_t)NODES * 4);
    int*   rowptr = (int*)  take((size_t)(NODES + 1) * 4);
    int*   cursor = (int*)  take((size_t)NODES * 4);
    int*   csr    = (int*)  take((size_t)ETOT * 4);
    float* sums   = (float*)take((size_t)NGRAPH * HDIM * 4);
    int*   cnt    = (int*)  take((size_t)NGRAPH * 4);
    float* h1     = (float*)take((size_t)NODES * HDIM * 4);  // h1, then reused for h2
    float* aggbuf = (float*)take((size_t)NODES * HDIM * 4);  // aggx (128) then aggh (256)

    const int NB = (NODES + 255) / 256;
    init_kernel <<<NB, 256, 0, stream>>>(deg, sums, cnt);
    count_kernel<<<(EDGES + 255) / 256, 256, 0, stream>>>(ecol, deg);
    node_kernel <<<NB, 256, 0, stream>>>(deg, bat, dinv, cnt);
    scan_kernel <<<1, 1024, 0, stream>>>(deg, rowptr, cursor);
    fill_kernel <<<(ETOT + 255) / 256, 256, 0, stream>>>(erow, ecol, cursor, csr);

    const int AGG_BLOCKS = (NODES * 64 + 255) / 256;  // one wave per node
    agg1_kernel<<<AGG_BLOCKS, 256, 0, stream>>>(x, rowptr, csr, dinv, aggbuf);

    const int MB = (NODES + 127) / 128;               // 782
    gemm_kernel<128><<<MB * 2, 256, 0, stream>>>(aggbuf, W1, b1, h1);

    agg2_kernel<<<AGG_BLOCKS, 256, 0, stream>>>(h1, rowptr, csr, dinv, aggbuf);

    gemm_kernel<256><<<MB * 2, 256, 0, stream>>>(aggbuf, W2, b2, h1);  // h1 buf = h2

    pool_kernel<<<dim3((NODES + 1023) / 1024, 4), 256, 0, stream>>>(h1, bat, sums);

    final_kernel<<<NGRAPH, 64, 0, stream>>>(sums, cnt, Wl, bl, out);
}

// Round 3
// 1542.654 us; speedup vs baseline: 2.0364x; 1.5296x over previous
//
#include <hip/hip_runtime.h>
#include <hip/hip_bf16.h>
#include <cstddef>

#define NODES  100000
#define EDGES  3200000
#define ETOT   3300000   // EDGES + NODES self-loops
#define NGRAPH 64
#define HDIM   256       // hidden dim (layers 1/2 output)

typedef __hip_bfloat16 bf16;

// ---------------------------------------------------------------- init / degree
__global__ void init_kernel(int* __restrict__ deg, float* __restrict__ sums) {
    int i = blockIdx.x * 256 + threadIdx.x;
    if (i < NODES) deg[i] = 1;                 // self-loop
    if (i < NGRAPH * HDIM) sums[i] = 0.f;
}

__global__ void count_kernel(const int* __restrict__ col, int* __restrict__ deg) {
    int e = blockIdx.x * 256 + threadIdx.x;
    if (e < EDGES) atomicAdd(&deg[col[e]], 1);
}

// dinv only — no atomics (cnt computed by binary search in final_kernel)
__global__ void node_kernel(const int* __restrict__ deg, float* __restrict__ dinv) {
    int i = blockIdx.x * 256 + threadIdx.x;
    if (i < NODES) dinv[i] = rsqrtf((float)deg[i]);   // deg >= 1 (self-loop)
}

// ---------------------------------------------------------------- fp32 -> bf16 copy of x
__global__ void xcast_kernel(const float* __restrict__ x, bf16* __restrict__ xb) {
    int i = blockIdx.x * 256 + threadIdx.x;            // handles 4 elements
    if ((size_t)i * 4 >= (size_t)NODES * 128) return;
    float4 v = *(const float4*)(x + (size_t)i * 4);
    union { __hip_bfloat162 h[2]; uint2 u; } pk;
    pk.h[0] = __float22bfloat162_rn(make_float2(v.x, v.y));
    pk.h[1] = __float22bfloat162_rn(make_float2(v.z, v.w));
    *(uint2*)(xb + (size_t)i * 4) = pk.u;
}

// ---------------------------------------------------------------- exclusive scan (1 block)
__global__ __launch_bounds__(1024) void scan_kernel(const int* __restrict__ deg,
                                                    int* __restrict__ rowptr,
                                                    int* __restrict__ cursor) {
    __shared__ int part[1024];
    int t = threadIdx.x;
    const int C = (NODES + 1023) / 1024;       // 98
    int lo = t * C;
    int hi = lo + C; if (hi > NODES) hi = NODES;
    int s = 0;
    for (int i = lo; i < hi; i++) s += deg[i];
    part[t] = s;
    __syncthreads();
    for (int off = 1; off < 1024; off <<= 1) {
        int v = (t >= off) ? part[t - off] : 0;
        __syncthreads();
        part[t] += v;
        __syncthreads();
    }
    int run = (t == 0) ? 0 : part[t - 1];
    for (int i = lo; i < hi; i++) { rowptr[i] = run; cursor[i] = run; run += deg[i]; }
    if (t == 1023) rowptr[NODES] = part[1023]; // == ETOT
}

// ---------------------------------------------------------------- CSR fill (dest-sorted)
__global__ void fill_kernel(const int* __restrict__ row, const int* __restrict__ col,
                            int* __restrict__ cursor, int* __restrict__ csr) {
    int e = blockIdx.x * 256 + threadIdx.x;
    if (e >= ETOT) return;
    int r, c;
    if (e < EDGES) { r = row[e]; c = col[e]; }
    else           { r = e - EDGES; c = r; }   // self-loop
    int pos = atomicAdd(&cursor[c], 1);
    csr[pos] = r;
}

// ---------------------------------------------------------------- pull aggregation, H=128 (bf16 src)
// out[v] = dinv[v] * sum_{e:col=v} dinv[src] * x[src]   (one wave per node)
__global__ void agg1_kernel(const bf16* __restrict__ xb, const int* __restrict__ rowptr,
                            const int* __restrict__ csr, const float* __restrict__ dinv,
                            float* __restrict__ out) {
    int w = (blockIdx.x * blockDim.x + threadIdx.x) >> 6;
    int lane = threadIdx.x & 63;
    if (w >= NODES) return;
    int beg = rowptr[w], end = rowptr[w + 1];
    float a0 = 0.f, a1 = 0.f;
    int j = beg;
    for (; j + 1 < end; j += 2) {
        int s0 = csr[j], s1 = csr[j + 1];
        float w0 = dinv[s0], w1 = dinv[s1];
        unsigned int q0 = *(const unsigned int*)(xb + (size_t)s0 * 128 + lane * 2);
        unsigned int q1 = *(const unsigned int*)(xb + (size_t)s1 * 128 + lane * 2);
        a0 += w0 * __uint_as_float(q0 << 16) + w1 * __uint_as_float(q1 << 16);
        a1 += w0 * __uint_as_float(q0 & 0xffff0000u) + w1 * __uint_as_float(q1 & 0xffff0000u);
    }
    if (j < end) {
        int s0 = csr[j];
        float w0 = dinv[s0];
        unsigned int q0 = *(const unsigned int*)(xb + (size_t)s0 * 128 + lane * 2);
        a0 += w0 * __uint_as_float(q0 << 16);
        a1 += w0 * __uint_as_float(q0 & 0xffff0000u);
    }
    float d = dinv[w];
    float2 o = {a0 * d, a1 * d};
    ((float2*)out)[(size_t)w * 64 + lane] = o;
}

// ---------------------------------------------------------------- pull aggregation, H=256 (bf16 src)
__global__ void agg2_kernel(const bf16* __restrict__ hb, const int* __restrict__ rowptr,
                            const int* __restrict__ csr, const float* __restrict__ dinv,
                            float* __restrict__ out) {
    int w = (blockIdx.x * blockDim.x + threadIdx.x) >> 6;
    int lane = threadIdx.x & 63;
    if (w >= NODES) return;
    int beg = rowptr[w], end = rowptr[w + 1];
    float a0 = 0.f, a1 = 0.f, a2 = 0.f, a3 = 0.f;
    int j = beg;
    for (; j + 1 < end; j += 2) {
        int s0 = csr[j], s1 = csr[j + 1];
        float w0 = dinv[s0], w1 = dinv[s1];
        uint2 q0 = *(const uint2*)(hb + (size_t)s0 * 256 + lane * 4);
        uint2 q1 = *(const uint2*)(hb + (size_t)s1 * 256 + lane * 4);
        a0 += w0 * __uint_as_float(q0.x << 16)        + w1 * __uint_as_float(q1.x << 16);
        a1 += w0 * __uint_as_float(q0.x & 0xffff0000u) + w1 * __uint_as_float(q1.x & 0xffff0000u);
        a2 += w0 * __uint_as_float(q0.y << 16)        + w1 * __uint_as_float(q1.y << 16);
        a3 += w0 * __uint_as_float(q0.y & 0xffff0000u) + w1 * __uint_as_float(q1.y & 0xffff0000u);
    }
    if (j < end) {
        int s0 = csr[j];
        float w0 = dinv[s0];
        uint2 q0 = *(const uint2*)(hb + (size_t)s0 * 256 + lane * 4);
        a0 += w0 * __uint_as_float(q0.x << 16);
        a1 += w0 * __uint_as_float(q0.x & 0xffff0000u);
        a2 += w0 * __uint_as_float(q0.y << 16);
        a3 += w0 * __uint_as_float(q0.y & 0xffff0000u);
    }
    float d = dinv[w];
    float4 o = {a0 * d, a1 * d, a2 * d, a3 * d};
    ((float4*)out)[(size_t)w * 64 + lane] = o;
}

// ---------------------------------------------------------------- fp32 GEMM 128x128, 8x8/thread
// C[M,256] = relu(A[M,K] @ B[K,256] + bias).  OUT_BF16: write bf16, else fp32.
template <int K, bool OUT_BF16>
__global__ __launch_bounds__(256) void gemm_kernel(const float* __restrict__ A,
                                                   const float* __restrict__ B,
                                                   const float* __restrict__ bias,
                                                   float* __restrict__ Cf,
                                                   bf16* __restrict__ Cb) {
    constexpr int BM = 128, BN = 128, BK = 16;
    __shared__ float As[BK][BM];   // transposed A tile: As[k][m]
    __shared__ float Bs[BK][BN];
    const int t  = threadIdx.x;
    const int bm = (int)(blockIdx.x >> 1) * BM;
    const int bn = (int)(blockIdx.x & 1) * BN;
    const int tx = t & 15, ty = t >> 4;
    float acc[8][8] = {};

    for (int k0 = 0; k0 < K; k0 += BK) {
        #pragma unroll
        for (int h = 0; h < 2; h++) {
            int q  = t * 2 + h;
            int m  = q >> 2;           // 0..127
            int k4 = (q & 3) * 4;      // 0,4,8,12
            int row = bm + m;
            float4 v = {0.f, 0.f, 0.f, 0.f};
            if (row < NODES) v = *(const float4*)(A + (size_t)row * K + k0 + k4);
            As[k4 + 0][m] = v.x; As[k4 + 1][m] = v.y;
            As[k4 + 2][m] = v.z; As[k4 + 3][m] = v.w;
        }
        #pragma unroll
        for (int h = 0; h < 2; h++) {
            int q  = t * 2 + h;
            int k  = q >> 5;           // 0..15
            int n4 = (q & 31) * 4;     // 0..124
            *(float4*)&Bs[k][n4] = *(const float4*)(B + (size_t)(k0 + k) * 256 + bn + n4);
        }
        __syncthreads();
        #pragma unroll
        for (int k = 0; k < BK; k++) {
            float a0[4], a1[4], b0[4], b1[4];
            *(float4*)a0 = *(const float4*)&As[k][ty * 4];
            *(float4*)a1 = *(const float4*)&As[k][64 + ty * 4];
            *(float4*)b0 = *(const float4*)&Bs[k][tx * 4];
            *(float4*)b1 = *(const float4*)&Bs[k][64 + tx * 4];
            #pragma unroll
            for (int i = 0; i < 4; i++) {
                #pragma unroll
                for (int j = 0; j < 4; j++) {
                    acc[i][j]         += a0[i] * b0[j];
                    acc[i][j + 4]     += a0[i] * b1[j];
                    acc[i + 4][j]     += a1[i] * b0[j];
                    acc[i + 4][j + 4] += a1[i] * b1[j];
                }
            }
        }
        __syncthreads();
    }

    #pragma unroll
    for (int ih = 0; ih < 2; ih++) {
        #pragma unroll
        for (int i = 0; i < 4; i++) {
            int row = bm + ih * 64 + ty * 4 + i;
            if (row >= NODES) continue;
            #pragma unroll
            for (int jh = 0; jh < 2; jh++) {
                int cb = bn + jh * 64 + tx * 4;
                float4 v;
                v.x = fmaxf(acc[ih * 4 + i][jh * 4 + 0] + bias[cb + 0], 0.f);
                v.y = fmaxf(acc[ih * 4 + i][jh * 4 + 1] + bias[cb + 1], 0.f);
                v.z = fmaxf(acc[ih * 4 + i][jh * 4 + 2] + bias[cb + 2], 0.f);
                v.w = fmaxf(acc[ih * 4 + i][jh * 4 + 3] + bias[cb + 3], 0.f);
                if (OUT_BF16) {
                    union { __hip_bfloat162 h[2]; uint2 u; } pk;
                    pk.h[0] = __float22bfloat162_rn(make_float2(v.x, v.y));
                    pk.h[1] = __float22bfloat162_rn(make_float2(v.z, v.w));
                    *(uint2*)(Cb + (size_t)row * 256 + cb) = pk.u;
                } else {
                    *(float4*)(Cf + (size_t)row * 256 + cb) = v;
                }
            }
        }
    }
}

// ---------------------------------------------------------------- segmented mean-pool sum
// batch is SORTED: per-thread register accumulation over a contiguous row chunk,
// one atomicAdd per graph-boundary crossing.
__global__ void pool_kernel(const float* __restrict__ h2, const int* __restrict__ batch,
                            float* __restrict__ sums) {
    int lane = threadIdx.x & 63;
    int sub  = threadIdx.x >> 6;                   // 0..3
    int col  = blockIdx.y * 64 + lane;
    int r0   = blockIdx.x * 1024 + sub * 256;
    if (r0 >= NODES) return;
    int r1 = r0 + 256; if (r1 > NODES) r1 = NODES;
    float acc = 0.f;
    int g = batch[r0];
    for (int r = r0; r < r1; r++) {
        int gg = batch[r];
        if (gg != g) { atomicAdd(&sums[g * 256 + col], acc); acc = 0.f; g = gg; }
        acc += h2[(size_t)r * 256 + col];
    }
    atomicAdd(&sums[g * 256 + col], acc);
}

// ---------------------------------------------------------------- pooled @ Wl + bl
// cnt[g] computed by binary search over the sorted batch array (no atomics).
__global__ void final_kernel(const float* __restrict__ sums, const int* __restrict__ batch,
                             const float* __restrict__ Wl, const float* __restrict__ bl,
                             float* __restrict__ out) {
    int g = blockIdx.x;
    int l = threadIdx.x;
    // lower bound: first i with batch[i] >= g
    int lo = 0, hi = NODES;
    while (lo < hi) { int m = (lo + hi) >> 1; if (batch[m] < g) lo = m + 1; else hi = m; }
    int lb = lo;
    // upper bound: first i with batch[i] > g
    lo = lb; hi = NODES;
    while (lo < hi) { int m = (lo + hi) >> 1; if (batch[m] <= g) lo = m + 1; else hi = m; }
    int cnt = lo - lb;
    float inv = 1.f / fmaxf((float)cnt, 1.f);
    float a0 = 0.f, a1 = 0.f;
    for (int k = l; k < 256; k += 64) {
        float p = sums[g * 256 + k] * inv;
        a0 += p * Wl[k * 2 + 0];
        a1 += p * Wl[k * 2 + 1];
    }
    for (int off = 32; off > 0; off >>= 1) {
        a0 += __shfl_down(a0, off, 64);
        a1 += __shfl_down(a1, off, 64);
    }
    if (l == 0) {
        out[g * 2 + 0] = a0 + bl[0];
        out[g * 2 + 1] = a1 + bl[1];
    }
}

// ---------------------------------------------------------------- launch
extern "C" void kernel_launch(void* const* d_in, const int* in_sizes, int n_in,
                              void* d_out, int out_size, void* d_ws, size_t ws_size,
                              hipStream_t stream) {
    const float* x    = (const float*)d_in[0];
    const int*   ei   = (const int*)d_in[1];
    const int*   bat  = (const int*)d_in[2];
    const float* W1   = (const float*)d_in[3];
    const float* b1   = (const float*)d_in[4];
    const float* W2   = (const float*)d_in[5];
    const float* b2   = (const float*)d_in[6];
    const float* Wl   = (const float*)d_in[7];
    const float* bl   = (const float*)d_in[8];
    float*       out  = (float*)d_out;
    const int* erow = ei;           // edge_index[0] = source
    const int* ecol = ei + EDGES;   // edge_index[1] = target

    char* p = (char*)d_ws;
    auto take = [&](size_t bytes) {
        char* r = p;
        p += (bytes + 255) & ~(size_t)255;
        return r;
    };
    int*   deg    = (int*)  take((size_t)NODES * 4);
    float* dinv   = (float*)take((size_t)NODES * 4);
    int*   rowptr = (int*)  take((size_t)(NODES + 1) * 4);
    int*   cursor = (int*)  take((size_t)NODES * 4);
    int*   csr    = (int*)  take((size_t)ETOT * 4);
    float* sums   = (float*)take((size_t)NGRAPH * HDIM * 4);
    float* aggbuf = (float*)take((size_t)NODES * HDIM * 4);  // agg outputs (fp32)
    char*  region = (char*) take((size_t)NODES * HDIM * 4);  // aliased: xb -> h1b -> h2
    bf16*  xb  = (bf16*)region;   // 25.6 MB, dead after agg1
    bf16*  h1b = (bf16*)region;   // 51.2 MB, dead after agg2
    float* h2  = (float*)region;  // 102.4 MB, dead after pool

    const int NB = (NODES + 255) / 256;
    init_kernel <<<NB, 256, 0, stream>>>(deg, sums);
    count_kernel<<<(EDGES + 255) / 256, 256, 0, stream>>>(ecol, deg);
    node_kernel <<<NB, 256, 0, stream>>>(deg, dinv);
    xcast_kernel<<<(NODES * 128 / 4 + 255) / 256, 256, 0, stream>>>(x, xb);
    scan_kernel <<<1, 1024, 0, stream>>>(deg, rowptr, cursor);
    fill_kernel <<<(ETOT + 255) / 256, 256, 0, stream>>>(erow, ecol, cursor, csr);

    const int AGG_BLOCKS = (NODES * 64 + 255) / 256;  // one wave per node
    agg1_kernel<<<AGG_BLOCKS, 256, 0, stream>>>(xb, rowptr, csr, dinv, aggbuf);

    const int MB = (NODES + 127) / 128;               // 782
    gemm_kernel<128, true><<<MB * 2, 256, 0, stream>>>(aggbuf, W1, b1, nullptr, h1b);

    agg2_kernel<<<AGG_BLOCKS, 256, 0, stream>>>(h1b, rowptr, csr, dinv, aggbuf);

    gemm_kernel<256, false><<<MB * 2, 256, 0, stream>>>(aggbuf, W2, b2, h2, nullptr);

    pool_kernel<<<dim3((NODES + 1023) / 1024, 4), 256, 0, stream>>>(h2, bat, sums);

    final_kernel<<<NGRAPH, 64, 0, stream>>>(sums, bat, Wl, bl, out);
}

// Round 4
// 1323.781 us; speedup vs baseline: 2.3731x; 1.1653x over previous
//
#include <hip/hip_runtime.h>
#include <hip/hip_bf16.h>
#include <cstddef>

#define NODES  100000
#define EDGES  3200000
#define ETOT   3300000   // EDGES + NODES self-loops
#define NGRAPH 64
#define HDIM   256
#define NBUCK  49        // dst >> 11 (2048 nodes/bucket)
#define BCAP   70656     // records per bucket: mean 67584 + 12 sigma

typedef __hip_bfloat16 bf16;
typedef short bf16x8 __attribute__((ext_vector_type(8)));
typedef float f32x4 __attribute__((ext_vector_type(4)));

// ---------------------------------------------------------------- init
__global__ void init_kernel(int* __restrict__ deg, float* __restrict__ sums,
                            int* __restrict__ gcnt) {
    int i = blockIdx.x * 256 + threadIdx.x;
    if (i < NODES) deg[i] = 1;                 // self-loop
    if (i < NGRAPH * HDIM) sums[i] = 0.f;
    if (i < NBUCK) gcnt[i] = 0;
}

__global__ void count_kernel(const int* __restrict__ col, int* __restrict__ deg) {
    int e = blockIdx.x * 256 + threadIdx.x;
    if (e < EDGES) atomicAdd(&deg[col[e]], 1);
}

__global__ void node_kernel(const int* __restrict__ deg, float* __restrict__ dinv) {
    int i = blockIdx.x * 256 + threadIdx.x;
    if (i < NODES) dinv[i] = rsqrtf((float)deg[i]);   // deg >= 1 (self-loop)
}

// ---------------------------------------------------------------- fp32 -> bf16 copy of x
__global__ void xcast_kernel(const float* __restrict__ x, bf16* __restrict__ xb) {
    int i = blockIdx.x * 256 + threadIdx.x;            // 4 elements each
    if ((size_t)i * 4 >= (size_t)NODES * 128) return;
    float4 v = *(const float4*)(x + (size_t)i * 4);
    union { __hip_bfloat162 h[2]; uint2 u; } pk;
    pk.h[0] = __float22bfloat162_rn(make_float2(v.x, v.y));
    pk.h[1] = __float22bfloat162_rn(make_float2(v.z, v.w));
    *(uint2*)(xb + (size_t)i * 4) = pk.u;
}

// ---------------------------------------------------------------- W[K,N] -> Wt[N,K] bf16
__global__ void wcast_kernel(const float* __restrict__ W, bf16* __restrict__ Wt, int K, int N) {
    int i = blockIdx.x * 256 + threadIdx.x;
    if (i >= K * N) return;
    int n = i / K, k = i - n * K;
    Wt[i] = __float2bfloat16(W[(size_t)k * N + n]);
}

// ---------------------------------------------------------------- exclusive scan (1 block)
__global__ __launch_bounds__(1024) void scan_kernel(const int* __restrict__ deg,
                                                    int* __restrict__ rowptr,
                                                    int* __restrict__ cursor) {
    __shared__ int part[1024];
    int t = threadIdx.x;
    const int C = (NODES + 1023) / 1024;       // 98
    int lo = t * C;
    int hi = lo + C; if (hi > NODES) hi = NODES;
    int s = 0;
    for (int i = lo; i < hi; i++) s += deg[i];
    part[t] = s;
    __syncthreads();
    for (int off = 1; off < 1024; off <<= 1) {
        int v = (t >= off) ? part[t - off] : 0;
        __syncthreads();
        part[t] += v;
        __syncthreads();
    }
    int run = (t == 0) ? 0 : part[t - 1];
    for (int i = lo; i < hi; i++) { rowptr[i] = run; cursor[i] = run; run += deg[i]; }
    if (t == 1023) rowptr[NODES] = part[1023]; // == ETOT
}

// ---------------------------------------------------------------- fill phase 1: bucket records
// Partition (src,dst) into 49 dst-buckets with block-level LDS aggregation:
// one global atomicAdd per (block,bucket); record writes are contiguous per block.
__global__ __launch_bounds__(256) void fillp1_kernel(const int* __restrict__ row,
                                                     const int* __restrict__ col,
                                                     int* __restrict__ gcnt,
                                                     uint2* __restrict__ recs) {
    __shared__ int hist[NBUCK];
    __shared__ int base[NBUCK];
    int t = threadIdx.x;
    if (t < NBUCK) hist[t] = 0;
    __syncthreads();
    int e0 = blockIdx.x * 4096;
    int r[16], c[16], rk[16];
    #pragma unroll
    for (int i = 0; i < 16; i++) {
        int e = e0 + i * 256 + t;
        r[i] = -1;
        if (e < ETOT) {
            if (e < EDGES) { r[i] = row[e]; c[i] = col[e]; }
            else           { r[i] = e - EDGES; c[i] = r[i]; }
            rk[i] = atomicAdd(&hist[c[i] >> 11], 1);
        }
    }
    __syncthreads();
    if (t < NBUCK && hist[t] > 0) base[t] = atomicAdd(&gcnt[t], hist[t]);
    __syncthreads();
    #pragma unroll
    for (int i = 0; i < 16; i++) {
        if (r[i] >= 0) {
            int b = c[i] >> 11;
            recs[(size_t)b * BCAP + base[b] + rk[i]] = make_uint2((unsigned)r[i], (unsigned)c[i]);
        }
    }
}

// ---------------------------------------------------------------- fill phase 2: L2-local scatter
// Scatter within one bucket: csr span ~270 KB -> L2-resident, lines fill fully.
__global__ void fillp2_kernel(const uint2* __restrict__ recs, const int* __restrict__ gcnt,
                              int* __restrict__ cursor, int* __restrict__ csr) {
    int b   = blockIdx.x >> 4;          // 16 blocks per bucket
    int sub = blockIdx.x & 15;
    int cnt = gcnt[b];
    for (int i = sub * 256 + threadIdx.x; i < cnt; i += 16 * 256) {
        uint2 rec = recs[(size_t)b * BCAP + i];
        int pos = atomicAdd(&cursor[rec.y], 1);
        csr[pos] = (int)rec.x;
    }
}

// ---------------------------------------------------------------- pull aggregation, H=128 (bf16 in/out)
__global__ void agg1_kernel(const bf16* __restrict__ xb, const int* __restrict__ rowptr,
                            const int* __restrict__ csr, const float* __restrict__ dinv,
                            bf16* __restrict__ out) {
    int w = (blockIdx.x * blockDim.x + threadIdx.x) >> 6;
    int lane = threadIdx.x & 63;
    if (w >= NODES) return;
    int beg = rowptr[w], end = rowptr[w + 1];
    float a0 = 0.f, a1 = 0.f;
    int j = beg;
    for (; j + 1 < end; j += 2) {
        int s0 = csr[j], s1 = csr[j + 1];
        float w0 = dinv[s0], w1 = dinv[s1];
        unsigned int q0 = *(const unsigned int*)(xb + (size_t)s0 * 128 + lane * 2);
        unsigned int q1 = *(const unsigned int*)(xb + (size_t)s1 * 128 + lane * 2);
        a0 += w0 * __uint_as_float(q0 << 16) + w1 * __uint_as_float(q1 << 16);
        a1 += w0 * __uint_as_float(q0 & 0xffff0000u) + w1 * __uint_as_float(q1 & 0xffff0000u);
    }
    if (j < end) {
        int s0 = csr[j];
        float w0 = dinv[s0];
        unsigned int q0 = *(const unsigned int*)(xb + (size_t)s0 * 128 + lane * 2);
        a0 += w0 * __uint_as_float(q0 << 16);
        a1 += w0 * __uint_as_float(q0 & 0xffff0000u);
    }
    float d = dinv[w];
    __hip_bfloat162 pk = __float22bfloat162_rn(make_float2(a0 * d, a1 * d));
    *(__hip_bfloat162*)(out + (size_t)w * 128 + lane * 2) = pk;
}

// ---------------------------------------------------------------- pull aggregation, H=256 (bf16 in/out)
__global__ void agg2_kernel(const bf16* __restrict__ hb, const int* __restrict__ rowptr,
                            const int* __restrict__ csr, const float* __restrict__ dinv,
                            bf16* __restrict__ out) {
    int w = (blockIdx.x * blockDim.x + threadIdx.x) >> 6;
    int lane = threadIdx.x & 63;
    if (w >= NODES) return;
    int beg = rowptr[w], end = rowptr[w + 1];
    float a0 = 0.f, a1 = 0.f, a2 = 0.f, a3 = 0.f;
    int j = beg;
    for (; j + 1 < end; j += 2) {
        int s0 = csr[j], s1 = csr[j + 1];
        float w0 = dinv[s0], w1 = dinv[s1];
        uint2 q0 = *(const uint2*)(hb + (size_t)s0 * 256 + lane * 4);
        uint2 q1 = *(const uint2*)(hb + (size_t)s1 * 256 + lane * 4);
        a0 += w0 * __uint_as_float(q0.x << 16)         + w1 * __uint_as_float(q1.x << 16);
        a1 += w0 * __uint_as_float(q0.x & 0xffff0000u) + w1 * __uint_as_float(q1.x & 0xffff0000u);
        a2 += w0 * __uint_as_float(q0.y << 16)         + w1 * __uint_as_float(q1.y << 16);
        a3 += w0 * __uint_as_float(q0.y & 0xffff0000u) + w1 * __uint_as_float(q1.y & 0xffff0000u);
    }
    if (j < end) {
        int s0 = csr[j];
        float w0 = dinv[s0];
        uint2 q0 = *(const uint2*)(hb + (size_t)s0 * 256 + lane * 4);
        a0 += w0 * __uint_as_float(q0.x << 16);
        a1 += w0 * __uint_as_float(q0.x & 0xffff0000u);
        a2 += w0 * __uint_as_float(q0.y << 16);
        a3 += w0 * __uint_as_float(q0.y & 0xffff0000u);
    }
    float d = dinv[w];
    union { __hip_bfloat162 h[2]; uint2 u; } pk;
    pk.h[0] = __float22bfloat162_rn(make_float2(a0 * d, a1 * d));
    pk.h[1] = __float22bfloat162_rn(make_float2(a2 * d, a3 * d));
    *(uint2*)(out + (size_t)w * 256 + lane * 4) = pk.u;
}

// ---------------------------------------------------------------- bf16 MFMA GEMM 128x128
// C[M,256] = relu(A[M,K] @ B[K,256] + bias).  A bf16 row-major, Bt = B^T bf16 (N x K).
// 4 waves, each 64x64 via 4x4 grid of mfma_f32_16x16x32_bf16.
template <int K, bool OUT_BF16>
__global__ __launch_bounds__(256) void mgemm_kernel(const bf16* __restrict__ A,
                                                    const bf16* __restrict__ Bt,
                                                    const float* __restrict__ bias,
                                                    float* __restrict__ Cf,
                                                    bf16* __restrict__ Cb) {
    __shared__ short As[128][40];   // [m][k], +8 pad breaks pow2 stride, keeps 16B align
    __shared__ short Bs[128][40];   // [n][k]
    const int t    = threadIdx.x;
    const int bm   = (int)(blockIdx.x >> 1) * 128;
    const int bn   = (int)(blockIdx.x & 1) * 128;
    const int lane = t & 63;
    const int wave = t >> 6;
    const int wm   = (wave >> 1) * 64, wn = (wave & 1) * 64;
    const int m16  = lane & 15, kq = lane >> 4;
    f32x4 acc[4][4] = {};

    for (int k0 = 0; k0 < K; k0 += 32) {
        #pragma unroll
        for (int h = 0; h < 2; h++) {
            int q = t * 2 + h;
            int rr = q >> 2, seg = q & 3;           // rr 0..127, seg*8 bf16 (16B)
            uint4 va = {0u, 0u, 0u, 0u};
            int grow = bm + rr;
            if (grow < NODES) va = *(const uint4*)(A + (size_t)grow * K + k0 + seg * 8);
            *(uint4*)&As[rr][seg * 8] = va;
            uint4 vb = *(const uint4*)(Bt + (size_t)(bn + rr) * K + k0 + seg * 8);
            *(uint4*)&Bs[rr][seg * 8] = vb;
        }
        __syncthreads();
        bf16x8 af[4], bf_[4];
        #pragma unroll
        for (int i = 0; i < 4; i++) {
            af[i]  = *(const bf16x8*)&As[wm + i * 16 + m16][kq * 8];
            bf_[i] = *(const bf16x8*)&Bs[wn + i * 16 + m16][kq * 8];
        }
        #pragma unroll
        for (int mt = 0; mt < 4; mt++)
            #pragma unroll
            for (int nt = 0; nt < 4; nt++)
                acc[mt][nt] = __builtin_amdgcn_mfma_f32_16x16x32_bf16(af[mt], bf_[nt],
                                                                     acc[mt][nt], 0, 0, 0);
        __syncthreads();
    }

    // C/D layout: col = lane&15, row = (lane>>4)*4 + reg
    #pragma unroll
    for (int mt = 0; mt < 4; mt++) {
        #pragma unroll
        for (int r = 0; r < 4; r++) {
            int row = bm + wm + mt * 16 + kq * 4 + r;
            if (row >= NODES) continue;
            #pragma unroll
            for (int nt = 0; nt < 4; nt++) {
                int colb = bn + wn + nt * 16 + m16;
                float v = fmaxf(acc[mt][nt][r] + bias[colb], 0.f);
                if (OUT_BF16) Cb[(size_t)row * 256 + colb] = __float2bfloat16(v);
                else          Cf[(size_t)row * 256 + colb] = v;
            }
        }
    }
}

// ---------------------------------------------------------------- segmented mean-pool sum
__global__ void pool_kernel(const float* __restrict__ h2, const int* __restrict__ batch,
                            float* __restrict__ sums) {
    int lane = threadIdx.x & 63;
    int sub  = threadIdx.x >> 6;                   // 0..3
    int col  = blockIdx.y * 64 + lane;
    int r0   = blockIdx.x * 1024 + sub * 256;
    if (r0 >= NODES) return;
    int r1 = r0 + 256; if (r1 > NODES) r1 = NODES;
    float acc = 0.f;
    int g = batch[r0];
    for (int r = r0; r < r1; r++) {
        int gg = batch[r];
        if (gg != g) { atomicAdd(&sums[g * 256 + col], acc); acc = 0.f; g = gg; }
        acc += h2[(size_t)r * 256 + col];
    }
    atomicAdd(&sums[g * 256 + col], acc);
}

// ---------------------------------------------------------------- pooled @ Wl + bl
__global__ void final_kernel(const float* __restrict__ sums, const int* __restrict__ batch,
                             const float* __restrict__ Wl, const float* __restrict__ bl,
                             float* __restrict__ out) {
    int g = blockIdx.x;
    int l = threadIdx.x;
    int lo = 0, hi = NODES;
    while (lo < hi) { int m = (lo + hi) >> 1; if (batch[m] < g) lo = m + 1; else hi = m; }
    int lb = lo;
    lo = lb; hi = NODES;
    while (lo < hi) { int m = (lo + hi) >> 1; if (batch[m] <= g) lo = m + 1; else hi = m; }
    int cnt = lo - lb;
    float inv = 1.f / fmaxf((float)cnt, 1.f);
    float a0 = 0.f, a1 = 0.f;
    for (int k = l; k < 256; k += 64) {
        float p = sums[g * 256 + k] * inv;
        a0 += p * Wl[k * 2 + 0];
        a1 += p * Wl[k * 2 + 1];
    }
    for (int off = 32; off > 0; off >>= 1) {
        a0 += __shfl_down(a0, off, 64);
        a1 += __shfl_down(a1, off, 64);
    }
    if (l == 0) {
        out[g * 2 + 0] = a0 + bl[0];
        out[g * 2 + 1] = a1 + bl[1];
    }
}

// ---------------------------------------------------------------- launch
extern "C" void kernel_launch(void* const* d_in, const int* in_sizes, int n_in,
                              void* d_out, int out_size, void* d_ws, size_t ws_size,
                              hipStream_t stream) {
    const float* x    = (const float*)d_in[0];
    const int*   ei   = (const int*)d_in[1];
    const int*   bat  = (const int*)d_in[2];
    const float* W1   = (const float*)d_in[3];
    const float* b1   = (const float*)d_in[4];
    const float* W2   = (const float*)d_in[5];
    const float* b2   = (const float*)d_in[6];
    const float* Wl   = (const float*)d_in[7];
    const float* bl   = (const float*)d_in[8];
    float*       out  = (float*)d_out;
    const int* erow = ei;           // edge_index[0] = source
    const int* ecol = ei + EDGES;   // edge_index[1] = target

    char* p = (char*)d_ws;
    auto take = [&](size_t bytes) {
        char* r = p;
        p += (bytes + 255) & ~(size_t)255;
        return r;
    };
    int*   deg    = (int*)  take((size_t)NODES * 4);
    float* dinv   = (float*)take((size_t)NODES * 4);
    int*   rowptr = (int*)  take((size_t)(NODES + 1) * 4);
    int*   cursor = (int*)  take((size_t)NODES * 4);
    int*   gcnt   = (int*)  take((size_t)NBUCK * 4);
    int*   csr    = (int*)  take((size_t)ETOT * 4);
    float* sums   = (float*)take((size_t)NGRAPH * HDIM * 4);
    bf16*  W1t    = (bf16*) take((size_t)128 * 256 * 2);
    bf16*  W2t    = (bf16*) take((size_t)256 * 256 * 2);
    char*  reg1   = (char*) take((size_t)NODES * HDIM * 2);  // 51.2MB: xb -> h1b
    char*  reg2   = (char*) take((size_t)NODES * HDIM * 2);  // 51.2MB: aggbuf1 -> aggbuf2
    char*  reg3   = (char*) take((size_t)NODES * HDIM * 4);  // 102.4MB: recs -> h2
    bf16*  xb      = (bf16*)reg1;    // dead after agg1
    bf16*  h1b     = (bf16*)reg1;    // born gemm1, dead after agg2
    bf16*  aggbuf1 = (bf16*)reg2;    // born agg1, dead after gemm1
    bf16*  aggbuf2 = (bf16*)reg2;    // born agg2, dead after gemm2
    uint2* recs    = (uint2*)reg3;   // dead after fillp2
    float* h2      = (float*)reg3;   // born gemm2

    const int NB = (NODES + 255) / 256;
    init_kernel <<<NB, 256, 0, stream>>>(deg, sums, gcnt);
    count_kernel<<<(EDGES + 255) / 256, 256, 0, stream>>>(ecol, deg);
    node_kernel <<<NB, 256, 0, stream>>>(deg, dinv);
    xcast_kernel<<<(NODES * 128 / 4 + 255) / 256, 256, 0, stream>>>(x, xb);
    wcast_kernel<<<(128 * 256 + 255) / 256, 256, 0, stream>>>(W1, W1t, 128, 256);
    wcast_kernel<<<(256 * 256 + 255) / 256, 256, 0, stream>>>(W2, W2t, 256, 256);

    fillp1_kernel<<<(ETOT + 4095) / 4096, 256, 0, stream>>>(erow, ecol, gcnt, recs);
    scan_kernel  <<<1, 1024, 0, stream>>>(deg, rowptr, cursor);
    fillp2_kernel<<<NBUCK * 16, 256, 0, stream>>>(recs, gcnt, cursor, csr);

    const int AGG_BLOCKS = (NODES * 64 + 255) / 256;  // one wave per node
    agg1_kernel<<<AGG_BLOCKS, 256, 0, stream>>>(xb, rowptr, csr, dinv, aggbuf1);

    const int MB = (NODES + 127) / 128;               // 782
    mgemm_kernel<128, true ><<<MB * 2, 256, 0, stream>>>(aggbuf1, W1t, b1, nullptr, h1b);

    agg2_kernel<<<AGG_BLOCKS, 256, 0, stream>>>(h1b, rowptr, csr, dinv, aggbuf2);

    mgemm_kernel<256, false><<<MB * 2, 256, 0, stream>>>(aggbuf2, W2t, b2, h2, nullptr);

    pool_kernel<<<dim3((NODES + 1023) / 1024, 4), 256, 0, stream>>>(h2, bat, sums);

    final_kernel<<<NGRAPH, 64, 0, stream>>>(sums, bat, Wl, bl, out);
}

// Round 5
// 739.254 us; speedup vs baseline: 4.2495x; 1.7907x over previous
//
#include <hip/hip_runtime.h>
#include <hip/hip_bf16.h>
#include <cstddef>

#define NODES  100000
#define EDGES  3200000
#define ETOT   3300000   // EDGES + NODES self-loops
#define NGRAPH 64
#define HDIM   256
#define BSHIFT 9
#define NBUCK  196       // ceil(NODES / 512)
#define BCAP   19456     // records/bucket: mean 16896, sigma ~130 -> +20 sigma

typedef __hip_bfloat16 bf16;
typedef short bf16x8 __attribute__((ext_vector_type(8)));
typedef float f32x4 __attribute__((ext_vector_type(4)));

__device__ __forceinline__ float blo(unsigned u) { return __uint_as_float(u << 16); }
__device__ __forceinline__ float bhi(unsigned u) { return __uint_as_float(u & 0xffff0000u); }

// ---------------------------------------------------------------- init
__global__ void init_kernel(float* __restrict__ sums, int* __restrict__ gcnt) {
    int i = blockIdx.x * 256 + threadIdx.x;
    if (i < NGRAPH * HDIM) sums[i] = 0.f;
    if (i < NBUCK) gcnt[i] = 0;
}

// ---------------------------------------------------------------- fp32 -> bf16 copy of x
__global__ void xcast_kernel(const float* __restrict__ x, bf16* __restrict__ xb) {
    int i = blockIdx.x * 256 + threadIdx.x;            // 4 elements each
    if ((size_t)i * 4 >= (size_t)NODES * 128) return;
    float4 v = *(const float4*)(x + (size_t)i * 4);
    union { __hip_bfloat162 h[2]; uint2 u; } pk;
    pk.h[0] = __float22bfloat162_rn(make_float2(v.x, v.y));
    pk.h[1] = __float22bfloat162_rn(make_float2(v.z, v.w));
    *(uint2*)(xb + (size_t)i * 4) = pk.u;
}

// ---------------------------------------------------------------- W[K,N] -> Wt[N,K] bf16
__global__ void wcast_kernel(const float* __restrict__ W, bf16* __restrict__ Wt, int K, int N) {
    int i = blockIdx.x * 256 + threadIdx.x;
    if (i >= K * N) return;
    int n = i / K, k = i - n * K;
    Wt[i] = __float2bfloat16(W[(size_t)k * N + n]);
}

// ---------------------------------------------------------------- fill phase 1: bucket records
// Partition (src,dst) into 196 dst-buckets (512 nodes each). Block-level LDS
// aggregation -> one global atomicAdd per (block,bucket); record writes are
// contiguous runs (~84 recs/bucket/block with 16K edges per block).
__global__ __launch_bounds__(1024) void fillp1_kernel(const int* __restrict__ row,
                                                      const int* __restrict__ col,
                                                      int* __restrict__ gcnt,
                                                      uint2* __restrict__ recs) {
    __shared__ int hist[NBUCK];
    __shared__ int base[NBUCK];
    int t = threadIdx.x;
    if (t < NBUCK) hist[t] = 0;
    __syncthreads();
    int e0 = blockIdx.x * 16384;
    int r[16], c[16], rk[16];
    #pragma unroll
    for (int i = 0; i < 16; i++) {
        int e = e0 + i * 1024 + t;
        r[i] = -1;
        if (e < ETOT) {
            if (e < EDGES) { r[i] = row[e]; c[i] = col[e]; }
            else           { r[i] = e - EDGES; c[i] = r[i]; }
            rk[i] = atomicAdd(&hist[c[i] >> BSHIFT], 1);
        }
    }
    __syncthreads();
    if (t < NBUCK && hist[t] > 0) base[t] = atomicAdd(&gcnt[t], hist[t]);
    __syncthreads();
    #pragma unroll
    for (int i = 0; i < 16; i++) {
        if (r[i] >= 0) {
            int b = c[i] >> BSHIFT;
            recs[(size_t)b * BCAP + base[b] + rk[i]] = make_uint2((unsigned)r[i], (unsigned)c[i]);
        }
    }
}

// ---------------------------------------------------------------- bucket base scan (tiny)
__global__ void bscan_kernel(const int* __restrict__ gcnt, int* __restrict__ bbase) {
    __shared__ int part[256];
    int t = threadIdx.x;
    int v0 = (t < NBUCK) ? gcnt[t] : 0;
    part[t] = v0;
    __syncthreads();
    for (int off = 1; off < 256; off <<= 1) {
        int v = (t >= off) ? part[t - off] : 0;
        __syncthreads();
        part[t] += v;
        __syncthreads();
    }
    if (t < NBUCK) bbase[t] = part[t] - v0;   // exclusive
}

// ---------------------------------------------------------------- per-bucket counting sort
// One WG per 512-node bucket: LDS histogram (-> deg -> dinv), LDS scan (-> rowptr),
// LDS-cursor scatter (-> csr, span ~67 KB = L2-local). Zero contended global atomics.
__global__ __launch_bounds__(256) void build_kernel(const uint2* __restrict__ recs,
                                                    const int* __restrict__ gcnt,
                                                    const int* __restrict__ bbase,
                                                    int* __restrict__ rowptr,
                                                    float* __restrict__ dinv,
                                                    int* __restrict__ csr) {
    __shared__ int hist[512];
    __shared__ int cur[512];
    __shared__ int part[256];
    const int b = blockIdx.x, t = threadIdx.x;
    const int n0 = b << BSHIFT;
    const int cnt = gcnt[b];
    const int base = bbase[b];
    hist[t] = 0; hist[t + 256] = 0;
    __syncthreads();
    const uint2* rb = recs + (size_t)b * BCAP;
    for (int i = t; i < cnt; i += 256) atomicAdd(&hist[(int)rb[i].y - n0], 1);
    __syncthreads();
    int h0 = hist[2 * t], h1 = hist[2 * t + 1];
    part[t] = h0 + h1;
    __syncthreads();
    for (int off = 1; off < 256; off <<= 1) {
        int v = (t >= off) ? part[t - off] : 0;
        __syncthreads();
        part[t] += v;
        __syncthreads();
    }
    int ex = (t == 0) ? 0 : part[t - 1];       // exclusive over node pairs
    cur[2 * t]     = ex;
    cur[2 * t + 1] = ex + h0;
    int v0 = n0 + 2 * t, v1 = v0 + 1;
    if (v0 < NODES) { rowptr[v0] = base + ex;      dinv[v0] = rsqrtf((float)h0); }
    if (v1 < NODES) { rowptr[v1] = base + ex + h0; dinv[v1] = rsqrtf((float)h1); }
    if (b == 0 && t == 0) rowptr[NODES] = ETOT;
    __syncthreads();
    for (int i = t; i < cnt; i += 256) {
        uint2 r = rb[i];
        int pos = atomicAdd(&cur[(int)r.y - n0], 1);
        csr[base + pos] = (int)r.x;
    }
}

// ---------------------------------------------------------------- pull aggregation, H=128
// 2 nodes per wave: half-wave (32 lanes) per node, uint2 (4 dims) per lane.
__global__ void agg1_kernel(const bf16* __restrict__ xb, const int* __restrict__ rowptr,
                            const int* __restrict__ csr, const float* __restrict__ dinv,
                            bf16* __restrict__ out) {
    int w    = (blockIdx.x * blockDim.x + threadIdx.x) >> 6;
    int lane = threadIdx.x & 63;
    int half = lane >> 5, li = lane & 31;
    int node = w * 2 + half;
    if (node >= NODES) return;
    int beg = rowptr[node], end = rowptr[node + 1];
    float a0 = 0.f, a1 = 0.f, a2 = 0.f, a3 = 0.f;
    int j = beg;
    for (; j + 1 < end; j += 2) {
        int s0 = csr[j], s1 = csr[j + 1];
        float w0 = dinv[s0], w1 = dinv[s1];
        uint2 q0 = *(const uint2*)(xb + (size_t)s0 * 128 + li * 4);
        uint2 q1 = *(const uint2*)(xb + (size_t)s1 * 128 + li * 4);
        a0 += w0 * blo(q0.x) + w1 * blo(q1.x);
        a1 += w0 * bhi(q0.x) + w1 * bhi(q1.x);
        a2 += w0 * blo(q0.y) + w1 * blo(q1.y);
        a3 += w0 * bhi(q0.y) + w1 * bhi(q1.y);
    }
    if (j < end) {
        int s0 = csr[j];
        float w0 = dinv[s0];
        uint2 q0 = *(const uint2*)(xb + (size_t)s0 * 128 + li * 4);
        a0 += w0 * blo(q0.x);
        a1 += w0 * bhi(q0.x);
        a2 += w0 * blo(q0.y);
        a3 += w0 * bhi(q0.y);
    }
    float d = dinv[node];
    union { __hip_bfloat162 h[2]; uint2 u; } pk;
    pk.h[0] = __float22bfloat162_rn(make_float2(a0 * d, a1 * d));
    pk.h[1] = __float22bfloat162_rn(make_float2(a2 * d, a3 * d));
    *(uint2*)(out + (size_t)node * 128 + li * 4) = pk.u;
}

// ---------------------------------------------------------------- pull aggregation, H=256
// 2 nodes per wave: half-wave per node, uint4 (8 dims) per lane.
__global__ void agg2_kernel(const bf16* __restrict__ hb, const int* __restrict__ rowptr,
                            const int* __restrict__ csr, const float* __restrict__ dinv,
                            bf16* __restrict__ out) {
    int w    = (blockIdx.x * blockDim.x + threadIdx.x) >> 6;
    int lane = threadIdx.x & 63;
    int half = lane >> 5, li = lane & 31;
    int node = w * 2 + half;
    if (node >= NODES) return;
    int beg = rowptr[node], end = rowptr[node + 1];
    float a[8] = {};
    int j = beg;
    for (; j + 1 < end; j += 2) {
        int s0 = csr[j], s1 = csr[j + 1];
        float w0 = dinv[s0], w1 = dinv[s1];
        uint4 q0 = *(const uint4*)(hb + (size_t)s0 * 256 + li * 8);
        uint4 q1 = *(const uint4*)(hb + (size_t)s1 * 256 + li * 8);
        a[0] += w0 * blo(q0.x) + w1 * blo(q1.x);
        a[1] += w0 * bhi(q0.x) + w1 * bhi(q1.x);
        a[2] += w0 * blo(q0.y) + w1 * blo(q1.y);
        a[3] += w0 * bhi(q0.y) + w1 * bhi(q1.y);
        a[4] += w0 * blo(q0.z) + w1 * blo(q1.z);
        a[5] += w0 * bhi(q0.z) + w1 * bhi(q1.z);
        a[6] += w0 * blo(q0.w) + w1 * blo(q1.w);
        a[7] += w0 * bhi(q0.w) + w1 * bhi(q1.w);
    }
    if (j < end) {
        int s0 = csr[j];
        float w0 = dinv[s0];
        uint4 q0 = *(const uint4*)(hb + (size_t)s0 * 256 + li * 8);
        a[0] += w0 * blo(q0.x); a[1] += w0 * bhi(q0.x);
        a[2] += w0 * blo(q0.y); a[3] += w0 * bhi(q0.y);
        a[4] += w0 * blo(q0.z); a[5] += w0 * bhi(q0.z);
        a[6] += w0 * blo(q0.w); a[7] += w0 * bhi(q0.w);
    }
    float d = dinv[node];
    union { __hip_bfloat162 h[4]; uint4 u; } pk;
    pk.h[0] = __float22bfloat162_rn(make_float2(a[0] * d, a[1] * d));
    pk.h[1] = __float22bfloat162_rn(make_float2(a[2] * d, a[3] * d));
    pk.h[2] = __float22bfloat162_rn(make_float2(a[4] * d, a[5] * d));
    pk.h[3] = __float22bfloat162_rn(make_float2(a[6] * d, a[7] * d));
    *(uint4*)(out + (size_t)node * 256 + li * 8) = pk.u;
}

// ---------------------------------------------------------------- bf16 MFMA GEMM 128x128
// C[M,256] = relu(A[M,K] @ B[K,256] + bias).  A bf16 row-major, Bt = B^T bf16 (N x K).
template <int K>
__global__ __launch_bounds__(256) void mgemm_kernel(const bf16* __restrict__ A,
                                                    const bf16* __restrict__ Bt,
                                                    const float* __restrict__ bias,
                                                    bf16* __restrict__ Cb) {
    __shared__ short As[128][40];   // [m][k], +8 pad breaks pow2 stride, keeps 16B align
    __shared__ short Bs[128][40];   // [n][k]
    const int t    = threadIdx.x;
    const int bm   = (int)(blockIdx.x >> 1) * 128;
    const int bn   = (int)(blockIdx.x & 1) * 128;
    const int lane = t & 63;
    const int wave = t >> 6;
    const int wm   = (wave >> 1) * 64, wn = (wave & 1) * 64;
    const int m16  = lane & 15, kq = lane >> 4;
    f32x4 acc[4][4] = {};

    for (int k0 = 0; k0 < K; k0 += 32) {
        #pragma unroll
        for (int h = 0; h < 2; h++) {
            int q = t * 2 + h;
            int rr = q >> 2, seg = q & 3;
            uint4 va = {0u, 0u, 0u, 0u};
            int grow = bm + rr;
            if (grow < NODES) va = *(const uint4*)(A + (size_t)grow * K + k0 + seg * 8);
            *(uint4*)&As[rr][seg * 8] = va;
            uint4 vb = *(const uint4*)(Bt + (size_t)(bn + rr) * K + k0 + seg * 8);
            *(uint4*)&Bs[rr][seg * 8] = vb;
        }
        __syncthreads();
        bf16x8 af[4], bf_[4];
        #pragma unroll
        for (int i = 0; i < 4; i++) {
            af[i]  = *(const bf16x8*)&As[wm + i * 16 + m16][kq * 8];
            bf_[i] = *(const bf16x8*)&Bs[wn + i * 16 + m16][kq * 8];
        }
        #pragma unroll
        for (int mt = 0; mt < 4; mt++)
            #pragma unroll
            for (int nt = 0; nt < 4; nt++)
                acc[mt][nt] = __builtin_amdgcn_mfma_f32_16x16x32_bf16(af[mt], bf_[nt],
                                                                     acc[mt][nt], 0, 0, 0);
        __syncthreads();
    }

    // C/D layout: col = lane&15, row = (lane>>4)*4 + reg
    #pragma unroll
    for (int mt = 0; mt < 4; mt++) {
        #pragma unroll
        for (int r = 0; r < 4; r++) {
            int row = bm + wm + mt * 16 + kq * 4 + r;
            if (row >= NODES) continue;
            #pragma unroll
            for (int nt = 0; nt < 4; nt++) {
                int colb = bn + wn + nt * 16 + m16;
                float v = fmaxf(acc[mt][nt][r] + bias[colb], 0.f);
                Cb[(size_t)row * 256 + colb] = __float2bfloat16(v);
            }
        }
    }
}

// ---------------------------------------------------------------- segmented mean-pool sum
// batch SORTED: per-thread register accumulation, one atomicAdd per boundary.
__global__ void pool_kernel(const bf16* __restrict__ h2, const int* __restrict__ batch,
                            float* __restrict__ sums) {
    int lane = threadIdx.x & 63;
    int sub  = threadIdx.x >> 6;                   // 0..3
    int col  = blockIdx.y * 64 + lane;
    int r0   = blockIdx.x * 1024 + sub * 256;
    if (r0 >= NODES) return;
    int r1 = r0 + 256; if (r1 > NODES) r1 = NODES;
    float acc = 0.f;
    int g = batch[r0];
    for (int r = r0; r < r1; r++) {
        int gg = batch[r];
        if (gg != g) { atomicAdd(&sums[g * 256 + col], acc); acc = 0.f; g = gg; }
        acc += __bfloat162float(h2[(size_t)r * 256 + col]);
    }
    atomicAdd(&sums[g * 256 + col], acc);
}

// ---------------------------------------------------------------- pooled @ Wl + bl
__global__ void final_kernel(const float* __restrict__ sums, const int* __restrict__ batch,
                             const float* __restrict__ Wl, const float* __restrict__ bl,
                             float* __restrict__ out) {
    int g = blockIdx.x;
    int l = threadIdx.x;
    int lo = 0, hi = NODES;
    while (lo < hi) { int m = (lo + hi) >> 1; if (batch[m] < g) lo = m + 1; else hi = m; }
    int lb = lo;
    lo = lb; hi = NODES;
    while (lo < hi) { int m = (lo + hi) >> 1; if (batch[m] <= g) lo = m + 1; else hi = m; }
    int cnt = lo - lb;
    float inv = 1.f / fmaxf((float)cnt, 1.f);
    float a0 = 0.f, a1 = 0.f;
    for (int k = l; k < 256; k += 64) {
        float p = sums[g * 256 + k] * inv;
        a0 += p * Wl[k * 2 + 0];
        a1 += p * Wl[k * 2 + 1];
    }
    for (int off = 32; off > 0; off >>= 1) {
        a0 += __shfl_down(a0, off, 64);
        a1 += __shfl_down(a1, off, 64);
    }
    if (l == 0) {
        out[g * 2 + 0] = a0 + bl[0];
        out[g * 2 + 1] = a1 + bl[1];
    }
}

// ---------------------------------------------------------------- launch
extern "C" void kernel_launch(void* const* d_in, const int* in_sizes, int n_in,
                              void* d_out, int out_size, void* d_ws, size_t ws_size,
                              hipStream_t stream) {
    const float* x    = (const float*)d_in[0];
    const int*   ei   = (const int*)d_in[1];
    const int*   bat  = (const int*)d_in[2];
    const float* W1   = (const float*)d_in[3];
    const float* b1   = (const float*)d_in[4];
    const float* W2   = (const float*)d_in[5];
    const float* b2   = (const float*)d_in[6];
    const float* Wl   = (const float*)d_in[7];
    const float* bl   = (const float*)d_in[8];
    float*       out  = (float*)d_out;
    const int* erow = ei;           // edge_index[0] = source
    const int* ecol = ei + EDGES;   // edge_index[1] = target

    char* p = (char*)d_ws;
    auto take = [&](size_t bytes) {
        char* r = p;
        p += (bytes + 255) & ~(size_t)255;
        return r;
    };
    float* dinv   = (float*)take((size_t)NODES * 4);
    int*   rowptr = (int*)  take((size_t)(NODES + 1) * 4);
    int*   gcnt   = (int*)  take((size_t)NBUCK * 4);
    int*   bbase  = (int*)  take((size_t)NBUCK * 4);
    int*   csr    = (int*)  take((size_t)ETOT * 4);
    float* sums   = (float*)take((size_t)NGRAPH * HDIM * 4);
    bf16*  W1t    = (bf16*) take((size_t)128 * 256 * 2);
    bf16*  W2t    = (bf16*) take((size_t)256 * 256 * 2);
    char*  reg1   = (char*) take((size_t)NODES * HDIM * 2);          // xb -> h1b
    char*  reg2   = (char*) take((size_t)NODES * HDIM * 2);          // aggbuf1 -> aggbuf2
    char*  reg3   = (char*) take((size_t)NBUCK * BCAP * 8 > (size_t)NODES * HDIM * 2
                                 ? (size_t)NBUCK * BCAP * 8 : (size_t)NODES * HDIM * 2); // recs -> h2b
    bf16*  xb      = (bf16*)reg1;    // dead after agg1
    bf16*  h1b     = (bf16*)reg1;    // born mgemm1, dead after agg2
    bf16*  aggbuf1 = (bf16*)reg2;    // born agg1, dead after mgemm1
    bf16*  aggbuf2 = (bf16*)reg2;    // born agg2, dead after mgemm2
    uint2* recs    = (uint2*)reg3;   // dead after build
    bf16*  h2b     = (bf16*)reg3;    // born mgemm2

    init_kernel <<<(NGRAPH * HDIM + 255) / 256, 256, 0, stream>>>(sums, gcnt);
    xcast_kernel<<<(NODES * 128 / 4 + 255) / 256, 256, 0, stream>>>(x, xb);
    wcast_kernel<<<(128 * 256 + 255) / 256, 256, 0, stream>>>(W1, W1t, 128, 256);
    wcast_kernel<<<(256 * 256 + 255) / 256, 256, 0, stream>>>(W2, W2t, 256, 256);

    fillp1_kernel<<<(ETOT + 16383) / 16384, 1024, 0, stream>>>(erow, ecol, gcnt, recs);
    bscan_kernel <<<1, 256, 0, stream>>>(gcnt, bbase);
    build_kernel <<<NBUCK, 256, 0, stream>>>(recs, gcnt, bbase, rowptr, dinv, csr);

    const int AGG_BLOCKS = (NODES / 2 * 64) / 256;    // 2 nodes per wave
    agg1_kernel<<<AGG_BLOCKS, 256, 0, stream>>>(xb, rowptr, csr, dinv, aggbuf1);

    const int MB = (NODES + 127) / 128;               // 782
    mgemm_kernel<128><<<MB * 2, 256, 0, stream>>>(aggbuf1, W1t, b1, h1b);

    agg2_kernel<<<AGG_BLOCKS, 256, 0, stream>>>(h1b, rowptr, csr, dinv, aggbuf2);

    mgemm_kernel<256><<<MB * 2, 256, 0, stream>>>(aggbuf2, W2t, b2, h2b);

    pool_kernel<<<dim3((NODES + 1023) / 1024, 4), 256, 0, stream>>>(h2b, bat, sums);

    final_kernel<<<NGRAPH, 64, 0, stream>>>(sums, bat, Wl, bl, out);
}